// Round 1
// baseline (451.445 us; speedup 1.0000x reference)
//
#include <hip/hip_runtime.h>
#include <math.h>

#define BB 4
#define NN 49104
#define CC 80
#define KPRE 1000
#define MAXB 100
#define NSLICE (BB*CC)
#define KEY_NEG1 0x407FFFFFu   // sortable key of -1.0f
#define CAP 4096

// ---------- helpers ----------
__device__ __forceinline__ unsigned f32_key(float f){
  unsigned u = __float_as_uint(f);
  return (u & 0x80000000u) ? ~u : (u | 0x80000000u);
}
__device__ __forceinline__ float key_f32(unsigned k){
  unsigned u = (k & 0x80000000u) ? (k ^ 0x80000000u) : ~k;
  return __uint_as_float(u);
}
// IoU(box_i, box_j) > 0.5, mirroring reference float32 op order exactly.
__device__ __forceinline__ bool iou_gt(float4 bi, float4 bj, float areaJ){
#pragma clang fp contract(off)
  float x1 = fmaxf(bi.x, bj.x);
  float y1 = fmaxf(bi.y, bj.y);
  float x2 = fminf(bi.z, bj.z);
  float y2 = fminf(bi.w, bj.w);
  float inter = fmaxf(x2 - x1, 0.0f) * fmaxf(y2 - y1, 0.0f);
  float areaI = (bi.z - bi.x) * (bi.w - bi.y);
  float iou = inter / ((areaI + areaJ) - inter);
  return iou > 0.5f;   // NaN -> false, same as jnp
}

// ---------- kernel 1: decode + clip boxes ----------
__global__ __launch_bounds__(256) void k_decode(const float* __restrict__ anchors,
    const float* __restrict__ regression, float4* __restrict__ boxes){
#pragma clang fp contract(off)
  int i = blockIdx.x * 256 + threadIdx.x;
  if (i >= BB*NN) return;
  float4 a = ((const float4*)anchors)[i];     // y1,x1,y2,x2
  float4 r = ((const float4*)regression)[i];  // dy,dx,dh,dw
  float yca = (a.x + a.z) * 0.5f;
  float xca = (a.y + a.w) * 0.5f;
  float ha = a.z - a.x;
  float wa = a.w - a.y;
  float w = (float)exp((double)r.w) * wa;
  float h = (float)exp((double)r.z) * ha;
  float yc = r.x * ha + yca;
  float xc = r.y * wa + xca;
  float hw = w * 0.5f, hh = h * 0.5f;
  float4 o;
  o.x = fmaxf(xc - hw, 0.0f);
  o.y = fmaxf(yc - hh, 0.0f);
  o.z = fminf(xc + hw, 511.0f);
  o.w = fminf(yc + hh, 511.0f);
  boxes[i] = o;
}

// ---------- kernel 2: sigmoid + threshold-mask + transpose to [B,C,N] sortable keys ----------
__global__ __launch_bounds__(256) void k_keys(const float* __restrict__ cls,
    unsigned* __restrict__ keysT){
  int b = blockIdx.y;
  int n0 = blockIdx.x * 64;
  __shared__ unsigned tile[64][81];   // +1 pad: conflict-free column reads
  int tid = threadIdx.x;
  for (int f = tid; f < 64*80; f += 256){
    int row = f / 80;
    int col = f - row*80;
    int n = n0 + row;
    unsigned key = KEY_NEG1;
    if (n < NN){
      float x = cls[((size_t)b*NN + n)*CC + col];
      double e = exp(-(double)x);
      float p = (float)(1.0 / (1.0 + e));
      key = (p > 0.01f) ? f32_key(p) : KEY_NEG1;
    }
    tile[row][col] = key;
  }
  __syncthreads();
  for (int f = tid; f < 64*80; f += 256){
    int i = f & 63;
    int c = f >> 6;
    int n = n0 + i;
    if (n < NN) keysT[((size_t)(b*CC + c))*NN + n] = tile[i][c];
  }
}

// ---------- kernel 3: per-slice exact top-1000 (sorted desc, index tie-break) ----------
__global__ __launch_bounds__(256) void k_select(const unsigned* __restrict__ keysT,
    float* __restrict__ tk_prob, int* __restrict__ tk_n){
  int s = blockIdx.x;
  const unsigned* base = keysT + (size_t)s * NN;
  __shared__ unsigned hist[4][256];
  __shared__ unsigned long long cand[CAP];
  __shared__ int sh_cnt;
  int tid = threadIdx.x;
  int wv = tid >> 6;

  unsigned prefix = 0; int G = 0; int lvl = 3;
  int shift = 24; int mode = 0;
  while (true){
    for (int i = tid; i < 4*256; i += 256) (&hist[0][0])[i] = 0u;
    __syncthreads();
    int sh8 = lvl * 8;
    bool top = (lvl == 3);
    for (int n = tid; n < NN; n += 256){
      unsigned k = base[n];
      bool match = top || ((k >> (sh8 + 8)) == prefix);
      if (match) atomicAdd(&hist[wv][(k >> sh8) & 255u], 1u);
    }
    __syncthreads();
    if (tid < 256)
      hist[0][tid] = hist[0][tid] + hist[1][tid] + hist[2][tid] + hist[3][tid];
    __syncthreads();
    // redundant identical scan on all threads
    int need = KPRE - G;
    int cum = 0, bstar = 0, cumBefore = 0, E = 0;
    for (int bin = 255; bin >= 0; bin--){
      int h = (int)hist[0][bin];
      if (cum + h >= need){ bstar = bin; cumBefore = cum; E = h; break; }
      cum += h;
    }
    prefix = top ? (unsigned)bstar : ((prefix << 8) | (unsigned)bstar);
    G += cumBefore;
    if (G + E <= CAP){ shift = sh8; mode = 0; break; }
    if (lvl == 0){ shift = 0; mode = 1; break; }
    lvl--;
    __syncthreads();
  }
  __syncthreads();
  if (tid == 0) sh_cnt = 0;
  __syncthreads();
  for (int n = tid; n < NN; n += 256){
    unsigned k = base[n];
    bool sel = (mode == 0) ? ((k >> shift) >= prefix) : (k > prefix);
    if (sel){
      int pos = atomicAdd(&sh_cnt, 1);
      if (pos < CAP) cand[pos] = ((unsigned long long)k << 32) | (unsigned)(~(unsigned)n);
    }
  }
  __syncthreads();
  int M = sh_cnt; if (M > CAP) M = CAP;
  if (mode == 1){
    // massive tie at boundary key (realistically only the -1.0 pad key):
    // strict-greater set (< 1000) is exact; pad the rest with the tied key.
    for (int i = M + tid; i < KPRE; i += 256)
      cand[i] = ((unsigned long long)prefix << 32) | 0xFFFFFFFFull;
    M = KPRE;
    __syncthreads();
  }
  int P = 1; while (P < M) P <<= 1;
  for (int i = M + tid; i < P; i += 256) cand[i] = 0ull;
  __syncthreads();
  // bitonic sort descending on u64 keys
  for (int kk = 2; kk <= P; kk <<= 1){
    for (int j = kk >> 1; j > 0; j >>= 1){
      for (int i = tid; i < P; i += 256){
        int l = i ^ j;
        if (l > i){
          unsigned long long a = cand[i], bq = cand[l];
          bool sw = ((i & kk) == 0) ? (a < bq) : (a > bq);
          if (sw){ cand[i] = bq; cand[l] = a; }
        }
      }
      __syncthreads();
    }
  }
  for (int i = tid; i < KPRE; i += 256){
    unsigned long long v = cand[i];
    unsigned k32 = (unsigned)(v >> 32);
    unsigned n = ~((unsigned)v);
    tk_prob[s*KPRE + i] = key_f32(k32);
    tk_n[s*KPRE + i] = (int)n;
  }
}

// ---------- kernel 4: per-slice greedy NMS (wave-ballot, 64-chunks, early-exit at 100 kept) ----------
__global__ __launch_bounds__(64) void k_nms(const float* __restrict__ tk_prob,
    const int* __restrict__ tk_n, const float4* __restrict__ boxes,
    int* __restrict__ nms_cnt, float* __restrict__ nms_score,
    int* __restrict__ nms_k, float4* __restrict__ nms_box){
  int s = blockIdx.x;
  int b = s / CC;
  __shared__ float4 sbox[1024];
  __shared__ float sprob[1024];
  __shared__ unsigned long long skept[16];
  int lane = threadIdx.x;
  for (int i = lane; i < 1024; i += 64){
    float p = -1.0f;
    float4 bx = make_float4(0.f,0.f,0.f,0.f);
    if (i < KPRE){
      p = tk_prob[s*KPRE + i];
      int n = tk_n[s*KPRE + i];
      bx = boxes[b*NN + n];
    }
    sprob[i] = p;
    sbox[i] = bx;
  }
  __syncthreads();
  int kcount = 0, tdone = 0;
  for (int t = 0; t < 16; t++){
    int gi = t*64 + lane;
    float4 me = sbox[gi];
    float myArea = (me.z - me.x) * (me.w - me.y);
    bool dead = !(sprob[gi] > 0.01f);
    // suppression by kept boxes of previous chunks (lazy)
    for (int p = 0; p < t; p++){
      unsigned long long m = skept[p];
      while (m){
        int i = __ffsll((unsigned long long)m) - 1;
        m &= (m - 1);
        if (iou_gt(sbox[p*64 + i], me, myArea)) dead = true;
      }
    }
    // intra-chunk pairwise bits (i < lane)
    unsigned long long supm = 0ull;
    for (int i = 0; i < 64; i++){
      if (iou_gt(sbox[t*64 + i], me, myArea)) supm |= (1ull << i);
    }
    supm &= ((1ull << lane) - 1ull);
    // serial greedy resolution via ballots (wave-uniform)
    unsigned long long keepb = __ballot(!dead);
    for (int i = 0; i < 64; i++){
      bool su = ((keepb >> i) & 1ull) && ((supm >> i) & 1ull);
      unsigned long long sb2 = __ballot(su ? 1 : 0);
      keepb &= ~sb2;
    }
    if (lane == 0) skept[t] = keepb;
    __syncthreads();
    kcount += __popcll(keepb);
    tdone = t + 1;
    if (kcount >= MAXB) break;   // 101st+ kept of a class can never enter image top-100
  }
  int outc = kcount < MAXB ? kcount : MAXB;
  if (lane == 0) nms_cnt[s] = outc;
  int pre = 0;
  for (int p = 0; p < tdone; p++){
    unsigned long long kb = skept[p];
    if ((kb >> lane) & 1ull){
      int rank = pre + __popcll(kb & ((1ull << lane) - 1ull));
      if (rank < MAXB){
        int posk = p*64 + lane;
        nms_score[s*MAXB + rank] = sprob[posk];
        nms_k[s*MAXB + rank] = posk;
        nms_box[s*MAXB + rank] = sbox[posk];
      }
    }
    pre += __popcll(kb);
  }
}

// ---------- kernel 5: per-image 80-way merge -> top-100, write outputs ----------
__global__ __launch_bounds__(256) void k_merge(const int* __restrict__ nms_cnt,
    const float* __restrict__ nms_score, const int* __restrict__ nms_k,
    const float4* __restrict__ nms_box, const float* __restrict__ scale,
    float* __restrict__ out){
  int b = blockIdx.x;
  __shared__ float ssc[CC*MAXB];
  __shared__ unsigned short skk[CC*MAXB];
  __shared__ int scnt[CC];
  __shared__ int out_cm[MAXB];
  __shared__ float out_sc[MAXB];
  __shared__ int sR;
  int tid = threadIdx.x;
  for (int i = tid; i < CC; i += 256) scnt[i] = nms_cnt[b*CC + i];
  __syncthreads();
  for (int i = tid; i < CC*MAXB; i += 256){
    int c = i / MAXB, m = i - c*MAXB;
    if (m < scnt[c]){
      int s = b*CC + c;
      ssc[i] = nms_score[s*MAXB + m];
      skk[i] = (unsigned short)nms_k[s*MAXB + m];
    }
  }
  __syncthreads();
  if (tid < 64){
    int lane = tid;
    int h0 = 0, h1 = 0;
    const int c0 = lane, c1 = 64 + lane;
    auto mkkey = [&](int c, int h) -> unsigned long long {
      if (c >= CC || h >= scnt[c]) return 0ull;
      unsigned fk = (unsigned)(c*KPRE + (int)skk[c*MAXB + h]);
      return ((unsigned long long)f32_key(ssc[c*MAXB + h]) << 32) | (0xFFFFFFFFu - fk);
    };
    unsigned long long key0 = mkkey(c0, h0);
    unsigned long long key1 = mkkey(c1, h1);
    int R = 0;
    for (int r = 0; r < MAXB; r++){
      unsigned long long best = key0 > key1 ? key0 : key1;
      #pragma unroll
      for (int off = 32; off > 0; off >>= 1){
        unsigned long long o = __shfl_xor(best, off, 64);
        if (o > best) best = o;
      }
      if (best == 0ull) break;
      if (key0 == best){
        out_cm[r] = c0*MAXB + h0; out_sc[r] = ssc[c0*MAXB + h0];
        h0++; key0 = mkkey(c0, h0);
      } else if (key1 == best){
        out_cm[r] = c1*MAXB + h1; out_sc[r] = ssc[c1*MAXB + h1];
        h1++; key1 = mkkey(c1, h1);
      }
      R = r + 1;
    }
    if (lane == 0) sR = R;
  }
  __syncthreads();
  int R = sR;
  float sb = scale[b];
  for (int r = tid; r < MAXB; r += 256){
    float4 bx = make_float4(0.f,0.f,0.f,0.f);
    float fs = 0.f, fc = -1.f;
    if (r < R){
      int cm = out_cm[r];
      int c = cm / MAXB, m = cm - c*MAXB;
      float4 v = nms_box[(b*CC + c)*MAXB + m];
      bx.x = v.x / sb; bx.y = v.y / sb; bx.z = v.z / sb; bx.w = v.w / sb;
      fs = out_sc[r];
      fc = (float)c;
    }
    ((float4*)out)[b*MAXB + r] = bx;                  // frois [B,100,4]
    out[BB*MAXB*4 + b*MAXB + r] = fc;                 // fcls  [B,100] (as float)
    out[BB*MAXB*5 + b*MAXB + r] = fs;                 // fsc   [B,100]
  }
}

// ---------- launch ----------
extern "C" void kernel_launch(void* const* d_in, const int* in_sizes, int n_in,
                              void* d_out, int out_size, void* d_ws, size_t ws_size,
                              hipStream_t stream) {
  const float* anchors    = (const float*)d_in[1];
  const float* regression = (const float*)d_in[2];
  const float* cls        = (const float*)d_in[3];
  const float* scale      = (const float*)d_in[4];
  float* out = (float*)d_out;

  char* ws = (char*)d_ws;
  size_t off = 0;
  float4*   boxes    = (float4*)(ws + off);   off += (size_t)BB*NN*16;        // 3,142,656
  unsigned* keysT    = (unsigned*)(ws + off); off += (size_t)NSLICE*NN*4;     // 62,853,120
  float*    tk_prob  = (float*)(ws + off);    off += (size_t)NSLICE*KPRE*4;   // 1,280,000
  int*      tk_n     = (int*)(ws + off);      off += (size_t)NSLICE*KPRE*4;   // 1,280,000
  int*      nms_cnt  = (int*)(ws + off);      off += (size_t)NSLICE*4;        // 1,280
  float*    nms_score= (float*)(ws + off);    off += (size_t)NSLICE*MAXB*4;   // 128,000
  int*      nms_k    = (int*)(ws + off);      off += (size_t)NSLICE*MAXB*4;   // 128,000
  float4*   nms_box  = (float4*)(ws + off);   off += (size_t)NSLICE*MAXB*16;  // 512,000
  if (ws_size < off) return;  // ~66.1 MiB required

  hipLaunchKernelGGL(k_decode, dim3((BB*NN + 255)/256), dim3(256), 0, stream,
                     anchors, regression, boxes);
  hipLaunchKernelGGL(k_keys, dim3((NN + 63)/64, BB), dim3(256), 0, stream,
                     cls, keysT);
  hipLaunchKernelGGL(k_select, dim3(NSLICE), dim3(256), 0, stream,
                     keysT, tk_prob, tk_n);
  hipLaunchKernelGGL(k_nms, dim3(NSLICE), dim3(64), 0, stream,
                     tk_prob, tk_n, (const float4*)boxes, nms_cnt, nms_score, nms_k, nms_box);
  hipLaunchKernelGGL(k_merge, dim3(BB), dim3(256), 0, stream,
                     nms_cnt, nms_score, nms_k, nms_box, scale, out);
}

// Round 2
// 307.343 us; speedup vs baseline: 1.4689x; 1.4689x over previous
//
#include <hip/hip_runtime.h>
#include <math.h>

#define BB 4
#define NN 49104
#define CC 80
#define KPRE 1000
#define MAXB 100
#define NSLICE (BB*CC)
#define KEY_NEG1 0x407FFFFFu   // sortable key of -1.0f
#define CAP 8192
#define NBIN 2048
#define CH 2
#define N4 (NN/4)              // 12276 uint4 per slice
#define CHUNK4 (N4/CH)         // 6138 uint4 per chunk

// ---------- helpers ----------
__device__ __forceinline__ unsigned f32_key(float f){
  unsigned u = __float_as_uint(f);
  return (u & 0x80000000u) ? ~u : (u | 0x80000000u);
}
__device__ __forceinline__ float key_f32(unsigned k){
  unsigned u = (k & 0x80000000u) ? (k ^ 0x80000000u) : ~k;
  return __uint_as_float(u);
}
// IoU(box_i, box_j) > 0.5, mirroring reference float32 op order exactly.
__device__ __forceinline__ bool iou_gt(float4 bi, float4 bj, float areaJ){
#pragma clang fp contract(off)
  float x1 = fmaxf(bi.x, bj.x);
  float y1 = fmaxf(bi.y, bj.y);
  float x2 = fminf(bi.z, bj.z);
  float y2 = fminf(bi.w, bj.w);
  float inter = fmaxf(x2 - x1, 0.0f) * fmaxf(y2 - y1, 0.0f);
  float areaI = (bi.z - bi.x) * (bi.w - bi.y);
  float iou = inter / ((areaI + areaJ) - inter);
  return iou > 0.5f;   // NaN -> false, same as jnp
}

// ---------- kernel 1: decode + clip boxes ----------
__global__ __launch_bounds__(256) void k_decode(const float* __restrict__ anchors,
    const float* __restrict__ regression, float4* __restrict__ boxes){
#pragma clang fp contract(off)
  int i = blockIdx.x * 256 + threadIdx.x;
  if (i >= BB*NN) return;
  float4 a = ((const float4*)anchors)[i];     // y1,x1,y2,x2
  float4 r = ((const float4*)regression)[i];  // dy,dx,dh,dw
  float yca = (a.x + a.z) * 0.5f;
  float xca = (a.y + a.w) * 0.5f;
  float ha = a.z - a.x;
  float wa = a.w - a.y;
  float w = (float)exp((double)r.w) * wa;
  float h = (float)exp((double)r.z) * ha;
  float yc = r.x * ha + yca;
  float xc = r.y * wa + xca;
  float hw = w * 0.5f, hh = h * 0.5f;
  float4 o;
  o.x = fmaxf(xc - hw, 0.0f);
  o.y = fmaxf(yc - hh, 0.0f);
  o.z = fminf(xc + hw, 511.0f);
  o.w = fminf(yc + hh, 511.0f);
  boxes[i] = o;
}

// ---------- kernel 2: sigmoid + threshold-mask + transpose to [B,C,N] sortable keys ----------
__global__ __launch_bounds__(256) void k_keys(const float* __restrict__ cls,
    unsigned* __restrict__ keysT){
  int b = blockIdx.y;
  int n0 = blockIdx.x * 64;
  __shared__ unsigned tile[64][81];   // +1 pad: conflict-free column reads
  int tid = threadIdx.x;
  for (int f = tid; f < 64*80; f += 256){
    int row = f / 80;
    int col = f - row*80;
    int n = n0 + row;
    unsigned key = KEY_NEG1;
    if (n < NN){
      float x = cls[((size_t)b*NN + n)*CC + col];
      double e = exp(-(double)x);
      float p = (float)(1.0 / (1.0 + e));
      key = (p > 0.01f) ? f32_key(p) : KEY_NEG1;
    }
    tile[row][col] = key;
  }
  __syncthreads();
  for (int f = tid; f < 64*80; f += 256){
    int i = f & 63;
    int c = f >> 6;
    int n = n0 + i;
    if (n < NN) keysT[((size_t)(b*CC + c))*NN + n] = tile[i][c];
  }
}

// ---------- kernel 3a: per-(slice,chunk) 2048-bin histogram over valid-key range ----------
__global__ __launch_bounds__(256) void k_hist(const uint4* __restrict__ keysT4,
    unsigned short* __restrict__ histc){
  int s = blockIdx.x;
  int ch = blockIdx.y;
  __shared__ unsigned h[NBIN];
  int tid = threadIdx.x;
  for (int i = tid; i < NBIN; i += 256) h[i] = 0u;
  __syncthreads();
  const uint4* base = keysT4 + (size_t)s * N4 + ch * CHUNK4;
  for (int i = tid; i < CHUNK4; i += 256){
    uint4 k4 = base[i];
    unsigned ks[4] = {k4.x, k4.y, k4.z, k4.w};
    #pragma unroll
    for (int j = 0; j < 4; j++){
      unsigned k = ks[j];
      // valid keys are in [0xBC23D70B, 0xBF800000]; invalid == KEY_NEG1
      if (k > KEY_NEG1) atomicAdd(&h[(k - 0xBC000000u) >> 15], 1u);
    }
  }
  __syncthreads();
  unsigned short* out = histc + ((size_t)s*CH + ch)*NBIN;
  for (int i = tid; i < NBIN; i += 256) out[i] = (unsigned short)h[i];
}

// ---------- kernel 3b: per-slice cutoff from histogram (suffix scan) ----------
__global__ __launch_bounds__(256) void k_cutoff(const unsigned short* __restrict__ histc,
    unsigned* __restrict__ cutKey, int* __restrict__ cutM){
  int s = blockIdx.x;
  __shared__ unsigned h[NBIN];
  __shared__ int sb;
  int tid = threadIdx.x;
  for (int i = tid; i < NBIN; i += 256){
    unsigned sum = 0;
    for (int c = 0; c < CH; c++) sum += histc[((size_t)s*CH + c)*NBIN + i];
    h[i] = sum;
  }
  if (tid == 0) sb = -1;
  __syncthreads();
  // inclusive suffix sum (Hillis-Steele): h[i] = count of keys in bins >= i
  for (int d = 1; d < NBIN; d <<= 1){
    unsigned v[NBIN/256];
    for (int i = tid, t = 0; i < NBIN; i += 256, t++)
      v[t] = h[i] + ((i + d < NBIN) ? h[i + d] : 0u);
    __syncthreads();
    for (int i = tid, t = 0; i < NBIN; i += 256, t++) h[i] = v[t];
    __syncthreads();
  }
  for (int i = tid; i < NBIN; i += 256){
    unsigned s0 = h[i];
    unsigned s1 = (i + 1 < NBIN) ? h[i + 1] : 0u;
    if (s0 >= KPRE && s1 < KPRE) sb = i;   // unique
  }
  __syncthreads();
  if (tid == 0){
    unsigned ck; int M;
    if ((int)h[0] < KPRE){           // fewer than KPRE valid: take all valid
      ck = KEY_NEG1 + 1; M = (int)h[0];
    } else {
      int b = sb;
      ck = 0xBC000000u + ((unsigned)b << 15);
      M = (int)h[b];
    }
    cutKey[s] = ck; cutM[s] = M;
  }
}

// ---------- kernel 3c: fused compact + bitonic sort + emit top-1000 ----------
__global__ __launch_bounds__(1024) void k_selsort(const unsigned* __restrict__ keysT,
    const unsigned* __restrict__ cutKey, const int* __restrict__ cutM,
    float* __restrict__ tk_prob, int* __restrict__ tk_n){
  int s = blockIdx.x;
  const unsigned* base = keysT + (size_t)s * NN;
  __shared__ unsigned long long cand[CAP];
  __shared__ unsigned hist[4][256];
  __shared__ int sh_cnt;
  int tid = threadIdx.x;
  unsigned ck = cutKey[s];
  int mode = 0;                       // 0: select k >= ck ; 1: select k > ck, pad ties
  if (cutM[s] > CAP){
    // generic fallback (degenerate tie distributions) — byte-level radix refinement
    unsigned prefix = 0; int G = 0; int lvl = 3;
    while (true){
      for (int i = tid; i < 4*256; i += 1024) (&hist[0][0])[i] = 0u;
      __syncthreads();
      int sh8 = lvl * 8;
      bool top = (lvl == 3);
      for (int n = tid; n < NN; n += 1024){
        unsigned k = base[n];
        bool match = top || ((k >> (sh8 + 8)) == prefix);
        if (match) atomicAdd(&hist[(tid >> 6) & 3][(k >> sh8) & 255u], 1u);
      }
      __syncthreads();
      if (tid < 256)
        hist[0][tid] = hist[0][tid] + hist[1][tid] + hist[2][tid] + hist[3][tid];
      __syncthreads();
      int need = KPRE - G;
      int cum = 0, bst = 0, cumB = 0, E = 0;
      for (int bin = 255; bin >= 0; bin--){
        int hh = (int)hist[0][bin];
        if (cum + hh >= need){ bst = bin; cumB = cum; E = hh; break; }
        cum += hh;
      }
      prefix = top ? (unsigned)bst : ((prefix << 8) | (unsigned)bst);
      G += cumB;
      if (G + E <= CAP){ mode = 0; ck = prefix << sh8; break; }
      if (lvl == 0){ mode = 1; ck = prefix; break; }
      lvl--;
      __syncthreads();
    }
    __syncthreads();
  }
  if (tid == 0) sh_cnt = 0;
  __syncthreads();
  // single coalesced compaction pass
  const uint4* b4 = (const uint4*)base;
  for (int i = tid; i < N4; i += 1024){
    uint4 k4 = b4[i];
    unsigned ks[4] = {k4.x, k4.y, k4.z, k4.w};
    #pragma unroll
    for (int j = 0; j < 4; j++){
      unsigned k = ks[j];
      bool sel = (mode == 0) ? (k >= ck) : (k > ck);
      if (sel){
        int pos = atomicAdd(&sh_cnt, 1);
        unsigned n = (unsigned)(i*4 + j);
        if (pos < CAP) cand[pos] = ((unsigned long long)k << 32) | (unsigned)(~n);
      }
    }
  }
  __syncthreads();
  int M = sh_cnt; if (M > CAP) M = CAP;
  // pad to KPRE (short slices: dead -1 entries; mode1: tied-key entries)
  unsigned padk = (mode == 1) ? ck : KEY_NEG1;
  for (int i = M + tid; i < KPRE; i += 1024)
    cand[i] = ((unsigned long long)padk << 32) | 0xFFFFFFFFull;
  if (M < KPRE) M = KPRE;
  __syncthreads();
  int P = 1; while (P < M) P <<= 1;
  for (int i = M + tid; i < P; i += 1024) cand[i] = 0ull;
  __syncthreads();
  // bitonic sort descending on u64 keys
  for (int kk = 2; kk <= P; kk <<= 1){
    for (int j = kk >> 1; j > 0; j >>= 1){
      for (int i = tid; i < P; i += 1024){
        int l = i ^ j;
        if (l > i){
          unsigned long long a = cand[i], bq = cand[l];
          bool sw = ((i & kk) == 0) ? (a < bq) : (a > bq);
          if (sw){ cand[i] = bq; cand[l] = a; }
        }
      }
      __syncthreads();
    }
  }
  for (int i = tid; i < KPRE; i += 1024){
    unsigned long long v = cand[i];
    unsigned k32 = (unsigned)(v >> 32);
    unsigned n = ~((unsigned)v);
    tk_prob[s*KPRE + i] = key_f32(k32);
    tk_n[s*KPRE + i] = (int)n;
  }
}

// ---------- kernel 4: per-slice greedy NMS (wave-ballot, 64-chunks, early-exit at 100 kept) ----------
__global__ __launch_bounds__(64) void k_nms(const float* __restrict__ tk_prob,
    const int* __restrict__ tk_n, const float4* __restrict__ boxes,
    int* __restrict__ nms_cnt, float* __restrict__ nms_score,
    int* __restrict__ nms_k){
  int s = blockIdx.x;
  int b = s / CC;
  __shared__ float4 sbox[1024];
  __shared__ float sprob[1024];
  __shared__ unsigned long long skept[16];
  int lane = threadIdx.x;
  for (int i = lane; i < 1024; i += 64){
    float p = -1.0f;
    float4 bx = make_float4(0.f,0.f,0.f,0.f);
    if (i < KPRE){
      p = tk_prob[s*KPRE + i];
      int n = tk_n[s*KPRE + i];
      bx = boxes[b*NN + n];
    }
    sprob[i] = p;
    sbox[i] = bx;
  }
  __syncthreads();
  int kcount = 0, tdone = 0;
  for (int t = 0; t < 16; t++){
    int gi = t*64 + lane;
    float4 me = sbox[gi];
    float myArea = (me.z - me.x) * (me.w - me.y);
    bool dead = !(sprob[gi] > 0.01f);
    for (int p = 0; p < t; p++){
      unsigned long long m = skept[p];
      while (m){
        int i = __ffsll((unsigned long long)m) - 1;
        m &= (m - 1);
        if (iou_gt(sbox[p*64 + i], me, myArea)) dead = true;
      }
    }
    unsigned long long supm = 0ull;
    for (int i = 0; i < 64; i++){
      if (iou_gt(sbox[t*64 + i], me, myArea)) supm |= (1ull << i);
    }
    supm &= ((1ull << lane) - 1ull);
    unsigned long long keepb = __ballot(!dead);
    for (int i = 0; i < 64; i++){
      bool su = ((keepb >> i) & 1ull) && ((supm >> i) & 1ull);
      unsigned long long sb2 = __ballot(su ? 1 : 0);
      keepb &= ~sb2;
    }
    if (lane == 0) skept[t] = keepb;
    __syncthreads();
    kcount += __popcll(keepb);
    tdone = t + 1;
    if (kcount >= MAXB) break;   // 101st+ kept of a class can never enter image top-100
  }
  int outc = kcount < MAXB ? kcount : MAXB;
  if (lane == 0) nms_cnt[s] = outc;
  int pre = 0;
  for (int p = 0; p < tdone; p++){
    unsigned long long kb = skept[p];
    if ((kb >> lane) & 1ull){
      int rank = pre + __popcll(kb & ((1ull << lane) - 1ull));
      if (rank < MAXB){
        int posk = p*64 + lane;
        nms_score[s*MAXB + rank] = sprob[posk];
        nms_k[s*MAXB + rank] = posk;
      }
    }
    pre += __popcll(kb);
  }
}

// ---------- kernel 5: per-image 80-way merge -> top-100, write outputs ----------
__global__ __launch_bounds__(256) void k_merge(const int* __restrict__ nms_cnt,
    const float* __restrict__ nms_score, const int* __restrict__ nms_k,
    const int* __restrict__ tk_n, const float4* __restrict__ boxes,
    const float* __restrict__ scale, float* __restrict__ out){
  int b = blockIdx.x;
  __shared__ float ssc[CC*MAXB];
  __shared__ unsigned short skk[CC*MAXB];
  __shared__ int scnt[CC];
  __shared__ int out_cm[MAXB];
  __shared__ float out_sc[MAXB];
  __shared__ int sR;
  int tid = threadIdx.x;
  for (int i = tid; i < CC; i += 256) scnt[i] = nms_cnt[b*CC + i];
  __syncthreads();
  for (int i = tid; i < CC*MAXB; i += 256){
    int c = i / MAXB, m = i - c*MAXB;
    if (m < scnt[c]){
      int s = b*CC + c;
      ssc[i] = nms_score[s*MAXB + m];
      skk[i] = (unsigned short)nms_k[s*MAXB + m];
    }
  }
  __syncthreads();
  if (tid < 64){
    int lane = tid;
    int h0 = 0, h1 = 0;
    const int c0 = lane, c1 = 64 + lane;
    auto mkkey = [&](int c, int h) -> unsigned long long {
      if (c >= CC || h >= scnt[c]) return 0ull;
      unsigned fk = (unsigned)(c*KPRE + (int)skk[c*MAXB + h]);
      return ((unsigned long long)f32_key(ssc[c*MAXB + h]) << 32) | (0xFFFFFFFFu - fk);
    };
    unsigned long long key0 = mkkey(c0, h0);
    unsigned long long key1 = mkkey(c1, h1);
    int R = 0;
    for (int r = 0; r < MAXB; r++){
      unsigned long long best = key0 > key1 ? key0 : key1;
      #pragma unroll
      for (int off = 32; off > 0; off >>= 1){
        unsigned long long o = __shfl_xor(best, off, 64);
        if (o > best) best = o;
      }
      if (best == 0ull) break;
      if (key0 == best){
        out_cm[r] = c0*MAXB + h0; out_sc[r] = ssc[c0*MAXB + h0];
        h0++; key0 = mkkey(c0, h0);
      } else if (key1 == best){
        out_cm[r] = c1*MAXB + h1; out_sc[r] = ssc[c1*MAXB + h1];
        h1++; key1 = mkkey(c1, h1);
      }
      R = r + 1;
    }
    if (lane == 0) sR = R;
  }
  __syncthreads();
  int R = sR;
  float sb = scale[b];
  for (int r = tid; r < MAXB; r += 256){
    float4 bx = make_float4(0.f,0.f,0.f,0.f);
    float fs = 0.f, fc = -1.f;
    if (r < R){
      int cm = out_cm[r];
      int c = cm / MAXB, m = cm - c*MAXB;
      int s = b*CC + c;
      int posk = (int)skk[cm];
      int n = tk_n[s*KPRE + posk];
      float4 v = boxes[b*NN + n];
      bx.x = v.x / sb; bx.y = v.y / sb; bx.z = v.z / sb; bx.w = v.w / sb;
      fs = out_sc[r];
      fc = (float)c;
    }
    ((float4*)out)[b*MAXB + r] = bx;                  // frois [B,100,4]
    out[BB*MAXB*4 + b*MAXB + r] = fc;                 // fcls  [B,100] (as float)
    out[BB*MAXB*5 + b*MAXB + r] = fs;                 // fsc   [B,100]
  }
}

// ---------- launch ----------
extern "C" void kernel_launch(void* const* d_in, const int* in_sizes, int n_in,
                              void* d_out, int out_size, void* d_ws, size_t ws_size,
                              hipStream_t stream) {
  const float* anchors    = (const float*)d_in[1];
  const float* regression = (const float*)d_in[2];
  const float* cls        = (const float*)d_in[3];
  const float* scale      = (const float*)d_in[4];
  float* out = (float*)d_out;

  char* ws = (char*)d_ws;
  // lifetimes (kernel order 1..7): boxes 1-7, keysT 2-5, histc 3-4, cutKey/M 4-5,
  // tk 5-7, nms 6-7.  A = histc | tk ; B = cutKey/M | nms  (stream-serialized reuse)
  size_t off = 0;
  float4*   boxes  = (float4*)(ws + off);   off += (size_t)BB*NN*16;        // 3,142,656
  unsigned* keysT  = (unsigned*)(ws + off); off += (size_t)NSLICE*NN*4;     // 62,853,120
  char* A = ws + off;
  size_t szA_hist = (size_t)NSLICE*CH*NBIN*2;                               // 2,621,440
  size_t szA_tk   = (size_t)NSLICE*KPRE*4 * 2;                              // 2,560,000
  off += (szA_hist > szA_tk ? szA_hist : szA_tk);
  char* Bp = ws + off;
  size_t szB_nms = (size_t)NSLICE*4 + (size_t)NSLICE*MAXB*4*2;              // 257,280
  size_t szB_cut = (size_t)NSLICE*4*2;                                      // 2,560
  off += (szB_nms > szB_cut ? szB_nms : szB_cut);
  if (ws_size < off) return;  // 68,874,496 bytes (< round-1's verified 69,325,056)

  unsigned short* histc = (unsigned short*)A;
  float* tk_prob = (float*)A;
  int*   tk_n    = (int*)(A + (size_t)NSLICE*KPRE*4);
  unsigned* cutKey = (unsigned*)Bp;
  int*      cutM   = (int*)(Bp + (size_t)NSLICE*4);
  int*   nms_cnt   = (int*)Bp;
  float* nms_score = (float*)(Bp + (size_t)NSLICE*4);
  int*   nms_k     = (int*)(Bp + (size_t)NSLICE*4 + (size_t)NSLICE*MAXB*4);

  hipLaunchKernelGGL(k_decode, dim3((BB*NN + 255)/256), dim3(256), 0, stream,
                     anchors, regression, boxes);
  hipLaunchKernelGGL(k_keys, dim3((NN + 63)/64, BB), dim3(256), 0, stream,
                     cls, keysT);
  hipLaunchKernelGGL(k_hist, dim3(NSLICE, CH), dim3(256), 0, stream,
                     (const uint4*)keysT, histc);
  hipLaunchKernelGGL(k_cutoff, dim3(NSLICE), dim3(256), 0, stream,
                     histc, cutKey, cutM);
  hipLaunchKernelGGL(k_selsort, dim3(NSLICE), dim3(1024), 0, stream,
                     keysT, cutKey, cutM, tk_prob, tk_n);
  hipLaunchKernelGGL(k_nms, dim3(NSLICE), dim3(64), 0, stream,
                     tk_prob, tk_n, (const float4*)boxes, nms_cnt, nms_score, nms_k);
  hipLaunchKernelGGL(k_merge, dim3(BB), dim3(256), 0, stream,
                     nms_cnt, nms_score, nms_k, tk_n, (const float4*)boxes, scale, out);
}

// Round 3
// 286.735 us; speedup vs baseline: 1.5744x; 1.0719x over previous
//
#include <hip/hip_runtime.h>
#include <math.h>

#define BB 4
#define NN 49104
#define CC 80
#define KPRE 1000
#define MAXB 100
#define NSLICE (BB*CC)
#define KEY_NEG1 0x407FFFFFu   // sortable key of -1.0f
#define CAP 8192
#define NBIN 2048
#define CH 2
#define N4 (NN/4)              // 12276 uint4 per slice
#define CHUNK4 (N4/CH)         // 6138 uint4 per chunk
#define MCAP 2048              // merge compact capacity

// ---------- helpers ----------
__device__ __forceinline__ unsigned f32_key(float f){
  unsigned u = __float_as_uint(f);
  return (u & 0x80000000u) ? ~u : (u | 0x80000000u);
}
__device__ __forceinline__ float key_f32(unsigned k){
  unsigned u = (k & 0x80000000u) ? (k ^ 0x80000000u) : ~k;
  return __uint_as_float(u);
}
// IoU(box_i, box_j) > 0.5, mirroring reference float32 op order exactly.
__device__ __forceinline__ bool iou_gt(float4 bi, float4 bj, float areaJ){
#pragma clang fp contract(off)
  float x1 = fmaxf(bi.x, bj.x);
  float y1 = fmaxf(bi.y, bj.y);
  float x2 = fminf(bi.z, bj.z);
  float y2 = fminf(bi.w, bj.w);
  float inter = fmaxf(x2 - x1, 0.0f) * fmaxf(y2 - y1, 0.0f);
  float areaI = (bi.z - bi.x) * (bi.w - bi.y);
  float iou = inter / ((areaI + areaJ) - inter);
  return iou > 0.5f;   // NaN -> false, same as jnp
}

// ---------- kernel 1: decode + clip boxes ----------
__global__ __launch_bounds__(256) void k_decode(const float* __restrict__ anchors,
    const float* __restrict__ regression, float4* __restrict__ boxes){
#pragma clang fp contract(off)
  int i = blockIdx.x * 256 + threadIdx.x;
  if (i >= BB*NN) return;
  float4 a = ((const float4*)anchors)[i];     // y1,x1,y2,x2
  float4 r = ((const float4*)regression)[i];  // dy,dx,dh,dw
  float yca = (a.x + a.z) * 0.5f;
  float xca = (a.y + a.w) * 0.5f;
  float ha = a.z - a.x;
  float wa = a.w - a.y;
  float w = (float)exp((double)r.w) * wa;
  float h = (float)exp((double)r.z) * ha;
  float yc = r.x * ha + yca;
  float xc = r.y * wa + xca;
  float hw = w * 0.5f, hh = h * 0.5f;
  float4 o;
  o.x = fmaxf(xc - hw, 0.0f);
  o.y = fmaxf(yc - hh, 0.0f);
  o.z = fminf(xc + hw, 511.0f);
  o.w = fminf(yc + hh, 511.0f);
  boxes[i] = o;
}

// ---------- kernel 2: sigmoid + threshold-mask + transpose to [B,C,N] sortable keys ----------
__global__ __launch_bounds__(256) void k_keys(const float* __restrict__ cls,
    unsigned* __restrict__ keysT){
  int b = blockIdx.y;
  int n0 = blockIdx.x * 64;
  __shared__ unsigned tile[64][81];   // +1 pad: conflict-free column reads
  int tid = threadIdx.x;
  for (int f = tid; f < 64*80; f += 256){
    int row = f / 80;
    int col = f - row*80;
    int n = n0 + row;
    unsigned key = KEY_NEG1;
    if (n < NN){
      float x = cls[((size_t)b*NN + n)*CC + col];
      double e = exp(-(double)x);
      float p = (float)(1.0 / (1.0 + e));
      key = (p > 0.01f) ? f32_key(p) : KEY_NEG1;
    }
    tile[row][col] = key;
  }
  __syncthreads();
  for (int f = tid; f < 64*80; f += 256){
    int i = f & 63;
    int c = f >> 6;
    int n = n0 + i;
    if (n < NN) keysT[((size_t)(b*CC + c))*NN + n] = tile[i][c];
  }
}

// ---------- kernel 3a: per-(slice,chunk) 2048-bin histogram over valid-key range ----------
__global__ __launch_bounds__(256) void k_hist(const uint4* __restrict__ keysT4,
    unsigned short* __restrict__ histc){
  int s = blockIdx.x;
  int ch = blockIdx.y;
  __shared__ unsigned h[NBIN];
  int tid = threadIdx.x;
  for (int i = tid; i < NBIN; i += 256) h[i] = 0u;
  __syncthreads();
  const uint4* base = keysT4 + (size_t)s * N4 + ch * CHUNK4;
  for (int i = tid; i < CHUNK4; i += 256){
    uint4 k4 = base[i];
    unsigned ks[4] = {k4.x, k4.y, k4.z, k4.w};
    #pragma unroll
    for (int j = 0; j < 4; j++){
      unsigned k = ks[j];
      // valid keys are in [0xBC23D70B, 0xBF800000]; invalid == KEY_NEG1
      if (k > KEY_NEG1) atomicAdd(&h[(k - 0xBC000000u) >> 15], 1u);
    }
  }
  __syncthreads();
  unsigned short* out = histc + ((size_t)s*CH + ch)*NBIN;
  for (int i = tid; i < NBIN; i += 256) out[i] = (unsigned short)h[i];
}

// ---------- kernel 3b: per-slice cutoff from histogram (suffix scan) ----------
__global__ __launch_bounds__(256) void k_cutoff(const unsigned short* __restrict__ histc,
    unsigned* __restrict__ cutKey, int* __restrict__ cutM){
  int s = blockIdx.x;
  __shared__ unsigned h[NBIN];
  __shared__ int sb;
  int tid = threadIdx.x;
  for (int i = tid; i < NBIN; i += 256){
    unsigned sum = 0;
    for (int c = 0; c < CH; c++) sum += histc[((size_t)s*CH + c)*NBIN + i];
    h[i] = sum;
  }
  if (tid == 0) sb = -1;
  __syncthreads();
  // inclusive suffix sum (Hillis-Steele): h[i] = count of keys in bins >= i
  for (int d = 1; d < NBIN; d <<= 1){
    unsigned v[NBIN/256];
    for (int i = tid, t = 0; i < NBIN; i += 256, t++)
      v[t] = h[i] + ((i + d < NBIN) ? h[i + d] : 0u);
    __syncthreads();
    for (int i = tid, t = 0; i < NBIN; i += 256, t++) h[i] = v[t];
    __syncthreads();
  }
  for (int i = tid; i < NBIN; i += 256){
    unsigned s0 = h[i];
    unsigned s1 = (i + 1 < NBIN) ? h[i + 1] : 0u;
    if (s0 >= KPRE && s1 < KPRE) sb = i;   // unique
  }
  __syncthreads();
  if (tid == 0){
    unsigned ck; int M;
    if ((int)h[0] < KPRE){           // fewer than KPRE valid: take all valid
      ck = KEY_NEG1 + 1; M = (int)h[0];
    } else {
      int b = sb;
      ck = 0xBC000000u + ((unsigned)b << 15);
      M = (int)h[b];
    }
    cutKey[s] = ck; cutM[s] = M;
  }
}

// ---------- kernel 3c: fused compact + bitonic sort + emit top-1000 ----------
__global__ __launch_bounds__(1024) void k_selsort(const unsigned* __restrict__ keysT,
    const unsigned* __restrict__ cutKey, const int* __restrict__ cutM,
    float* __restrict__ tk_prob, int* __restrict__ tk_n){
  int s = blockIdx.x;
  const unsigned* base = keysT + (size_t)s * NN;
  __shared__ unsigned long long cand[CAP];
  __shared__ unsigned hist[4][256];
  __shared__ int sh_cnt;
  int tid = threadIdx.x;
  unsigned ck = cutKey[s];
  int mode = 0;                       // 0: select k >= ck ; 1: select k > ck, pad ties
  if (cutM[s] > CAP){
    // generic fallback (degenerate tie distributions) — byte-level radix refinement
    unsigned prefix = 0; int G = 0; int lvl = 3;
    while (true){
      for (int i = tid; i < 4*256; i += 1024) (&hist[0][0])[i] = 0u;
      __syncthreads();
      int sh8 = lvl * 8;
      bool top = (lvl == 3);
      for (int n = tid; n < NN; n += 1024){
        unsigned k = base[n];
        bool match = top || ((k >> (sh8 + 8)) == prefix);
        if (match) atomicAdd(&hist[(tid >> 6) & 3][(k >> sh8) & 255u], 1u);
      }
      __syncthreads();
      if (tid < 256)
        hist[0][tid] = hist[0][tid] + hist[1][tid] + hist[2][tid] + hist[3][tid];
      __syncthreads();
      int need = KPRE - G;
      int cum = 0, bst = 0, cumB = 0, E = 0;
      for (int bin = 255; bin >= 0; bin--){
        int hh = (int)hist[0][bin];
        if (cum + hh >= need){ bst = bin; cumB = cum; E = hh; break; }
        cum += hh;
      }
      prefix = top ? (unsigned)bst : ((prefix << 8) | (unsigned)bst);
      G += cumB;
      if (G + E <= CAP){ mode = 0; ck = prefix << sh8; break; }
      if (lvl == 0){ mode = 1; ck = prefix; break; }
      lvl--;
      __syncthreads();
    }
    __syncthreads();
  }
  if (tid == 0) sh_cnt = 0;
  __syncthreads();
  // single coalesced compaction pass
  const uint4* b4 = (const uint4*)base;
  for (int i = tid; i < N4; i += 1024){
    uint4 k4 = b4[i];
    unsigned ks[4] = {k4.x, k4.y, k4.z, k4.w};
    #pragma unroll
    for (int j = 0; j < 4; j++){
      unsigned k = ks[j];
      bool sel = (mode == 0) ? (k >= ck) : (k > ck);
      if (sel){
        int pos = atomicAdd(&sh_cnt, 1);
        unsigned n = (unsigned)(i*4 + j);
        if (pos < CAP) cand[pos] = ((unsigned long long)k << 32) | (unsigned)(~n);
      }
    }
  }
  __syncthreads();
  int M = sh_cnt; if (M > CAP) M = CAP;
  // pad to KPRE (short slices: dead -1 entries; mode1: tied-key entries)
  unsigned padk = (mode == 1) ? ck : KEY_NEG1;
  for (int i = M + tid; i < KPRE; i += 1024)
    cand[i] = ((unsigned long long)padk << 32) | 0xFFFFFFFFull;
  if (M < KPRE) M = KPRE;
  __syncthreads();
  int P = 1; while (P < M) P <<= 1;
  for (int i = M + tid; i < P; i += 1024) cand[i] = 0ull;
  __syncthreads();
  // bitonic sort descending on u64 keys
  for (int kk = 2; kk <= P; kk <<= 1){
    for (int j = kk >> 1; j > 0; j >>= 1){
      for (int i = tid; i < P; i += 1024){
        int l = i ^ j;
        if (l > i){
          unsigned long long a = cand[i], bq = cand[l];
          bool sw = ((i & kk) == 0) ? (a < bq) : (a > bq);
          if (sw){ cand[i] = bq; cand[l] = a; }
        }
      }
      __syncthreads();
    }
  }
  for (int i = tid; i < KPRE; i += 1024){
    unsigned long long v = cand[i];
    unsigned k32 = (unsigned)(v >> 32);
    unsigned n = ~((unsigned)v);
    tk_prob[s*KPRE + i] = key_f32(k32);
    tk_n[s*KPRE + i] = (int)n;
  }
}

// ---------- kernel 4: per-slice greedy NMS (wave-ballot, 64-chunks, early-exit at 100 kept) ----------
__global__ __launch_bounds__(64) void k_nms(const float* __restrict__ tk_prob,
    const int* __restrict__ tk_n, const float4* __restrict__ boxes,
    int* __restrict__ nms_cnt, float* __restrict__ nms_score,
    int* __restrict__ nms_k){
  int s = blockIdx.x;
  int b = s / CC;
  __shared__ float4 sbox[1024];
  __shared__ float sprob[1024];
  __shared__ unsigned long long skept[16];
  int lane = threadIdx.x;
  for (int i = lane; i < 1024; i += 64){
    float p = -1.0f;
    float4 bx = make_float4(0.f,0.f,0.f,0.f);
    if (i < KPRE){
      p = tk_prob[s*KPRE + i];
      int n = tk_n[s*KPRE + i];
      bx = boxes[b*NN + n];
    }
    sprob[i] = p;
    sbox[i] = bx;
  }
  __syncthreads();
  int kcount = 0, tdone = 0;
  for (int t = 0; t < 16; t++){
    int gi = t*64 + lane;
    float4 me = sbox[gi];
    float myArea = (me.z - me.x) * (me.w - me.y);
    bool dead = !(sprob[gi] > 0.01f);
    for (int p = 0; p < t; p++){
      unsigned long long m = skept[p];
      while (m){
        int i = __ffsll((unsigned long long)m) - 1;
        m &= (m - 1);
        if (iou_gt(sbox[p*64 + i], me, myArea)) dead = true;
      }
    }
    unsigned long long supm = 0ull;
    for (int i = 0; i < 64; i++){
      if (iou_gt(sbox[t*64 + i], me, myArea)) supm |= (1ull << i);
    }
    supm &= ((1ull << lane) - 1ull);
    unsigned long long keepb = __ballot(!dead);
    for (int i = 0; i < 64; i++){
      bool su = ((keepb >> i) & 1ull) && ((supm >> i) & 1ull);
      unsigned long long sb2 = __ballot(su ? 1 : 0);
      keepb &= ~sb2;
    }
    if (lane == 0) skept[t] = keepb;
    __syncthreads();
    kcount += __popcll(keepb);
    tdone = t + 1;
    if (kcount >= MAXB) break;   // 101st+ kept of a class can never enter image top-100
  }
  int outc = kcount < MAXB ? kcount : MAXB;
  if (lane == 0) nms_cnt[s] = outc;
  int pre = 0;
  for (int p = 0; p < tdone; p++){
    unsigned long long kb = skept[p];
    if ((kb >> lane) & 1ull){
      int rank = pre + __popcll(kb & ((1ull << lane) - 1ull));
      if (rank < MAXB){
        int posk = p*64 + lane;
        nms_score[s*MAXB + rank] = sprob[posk];
        nms_k[s*MAXB + rank] = posk;
      }
    }
    pre += __popcll(kb);
  }
}

// ---------- kernel 5: per-image top-100 via histogram select (parallel, no serial merge) ----------
__global__ __launch_bounds__(256) void k_merge(const int* __restrict__ nms_cnt,
    const float* __restrict__ nms_score, const int* __restrict__ nms_k,
    const int* __restrict__ tk_n, const float4* __restrict__ boxes,
    const float* __restrict__ scale, float* __restrict__ out){
  int b = blockIdx.x;
  __shared__ int scnt[CC];
  __shared__ unsigned h[NBIN];              // 8 KB
  __shared__ unsigned long long cand[MCAP]; // 16 KB
  __shared__ int sh_cnt, sbv;
  int tid = threadIdx.x;
  for (int i = tid; i < CC; i += 256) scnt[i] = nms_cnt[b*CC + i];
  for (int i = tid; i < NBIN; i += 256) h[i] = 0u;
  if (tid == 0){ sh_cnt = 0; sbv = -1; }
  __syncthreads();
  // histogram of kept-score keys (all kept scores are > 0.01 by construction)
  for (int i = tid; i < CC*MAXB; i += 256){
    int c = i / MAXB, m = i - c*MAXB;
    if (m < scnt[c]){
      unsigned k = f32_key(nms_score[(b*CC + c)*MAXB + m]);
      atomicAdd(&h[(k - 0xBC000000u) >> 15], 1u);
    }
  }
  __syncthreads();
  // inclusive suffix sum: h[i] = # keys in bins >= i
  for (int d = 1; d < NBIN; d <<= 1){
    unsigned v[NBIN/256];
    for (int i = tid, t = 0; i < NBIN; i += 256, t++)
      v[t] = h[i] + ((i + d < NBIN) ? h[i + d] : 0u);
    __syncthreads();
    for (int i = tid, t = 0; i < NBIN; i += 256, t++) h[i] = v[t];
    __syncthreads();
  }
  for (int i = tid; i < NBIN; i += 256){
    unsigned s0 = h[i];
    unsigned s1 = (i + 1 < NBIN) ? h[i + 1] : 0u;
    if (s0 >= MAXB && s1 < MAXB) sbv = i;
  }
  __syncthreads();
  int total = (int)h[0];
  unsigned cutk = (total >= MAXB) ? (0xBC000000u + ((unsigned)sbv << 15)) : 0u;
  // compact candidates >= cutoff  (M = h[sbv] ~ 100+binload; MCAP overflow only under
  // degenerate mass-tie score distributions, not present for this workload)
  for (int i = tid; i < CC*MAXB; i += 256){
    int c = i / MAXB, m = i - c*MAXB;
    if (m < scnt[c]){
      unsigned k = f32_key(nms_score[(b*CC + c)*MAXB + m]);
      if (k >= cutk){
        int pos = atomicAdd(&sh_cnt, 1);
        unsigned fk = (unsigned)(c*KPRE + nms_k[(b*CC + c)*MAXB + m]);
        if (pos < MCAP) cand[pos] = ((unsigned long long)k << 32) | (0xFFFFFFFFu - fk);
      }
    }
  }
  __syncthreads();
  int M = sh_cnt; if (M > MCAP) M = MCAP;
  int P = 128; while (P < M) P <<= 1;
  for (int i = M + tid; i < P; i += 256) cand[i] = 0ull;
  __syncthreads();
  // bitonic sort descending
  for (int kk = 2; kk <= P; kk <<= 1){
    for (int j = kk >> 1; j > 0; j >>= 1){
      for (int i = tid; i < P; i += 256){
        int l = i ^ j;
        if (l > i){
          unsigned long long a = cand[i], bq = cand[l];
          bool sw = ((i & kk) == 0) ? (a < bq) : (a > bq);
          if (sw){ cand[i] = bq; cand[l] = a; }
        }
      }
      __syncthreads();
    }
  }
  int R = total < MAXB ? total : MAXB;
  float sb = scale[b];
  for (int r = tid; r < MAXB; r += 256){
    float4 bx = make_float4(0.f,0.f,0.f,0.f);
    float fs = 0.f, fc = -1.f;
    if (r < R){
      unsigned long long v = cand[r];
      unsigned k32 = (unsigned)(v >> 32);
      unsigned fk = 0xFFFFFFFFu - (unsigned)v;
      int c = fk / KPRE, posk = fk - (fk / KPRE) * KPRE;
      int n = tk_n[((size_t)(b*CC + c))*KPRE + posk];
      float4 w = boxes[b*NN + n];
      bx.x = w.x / sb; bx.y = w.y / sb; bx.z = w.z / sb; bx.w = w.w / sb;
      fs = key_f32(k32);
      fc = (float)c;
    }
    ((float4*)out)[b*MAXB + r] = bx;                  // frois [B,100,4]
    out[BB*MAXB*4 + b*MAXB + r] = fc;                 // fcls  [B,100] (as float)
    out[BB*MAXB*5 + b*MAXB + r] = fs;                 // fsc   [B,100]
  }
}

// ---------- launch ----------
extern "C" void kernel_launch(void* const* d_in, const int* in_sizes, int n_in,
                              void* d_out, int out_size, void* d_ws, size_t ws_size,
                              hipStream_t stream) {
  const float* anchors    = (const float*)d_in[1];
  const float* regression = (const float*)d_in[2];
  const float* cls        = (const float*)d_in[3];
  const float* scale      = (const float*)d_in[4];
  float* out = (float*)d_out;

  char* ws = (char*)d_ws;
  // lifetimes (kernel order 1..7): boxes 1-7, keysT 2-5, histc 3-4, cutKey/M 4-5,
  // tk 5-7, nms 6-7.  A = histc | tk ; B = cutKey/M | nms  (stream-serialized reuse)
  size_t off = 0;
  float4*   boxes  = (float4*)(ws + off);   off += (size_t)BB*NN*16;        // 3,142,656
  unsigned* keysT  = (unsigned*)(ws + off); off += (size_t)NSLICE*NN*4;     // 62,853,120
  char* A = ws + off;
  size_t szA_hist = (size_t)NSLICE*CH*NBIN*2;                               // 2,621,440
  size_t szA_tk   = (size_t)NSLICE*KPRE*4 * 2;                              // 2,560,000
  off += (szA_hist > szA_tk ? szA_hist : szA_tk);
  char* Bp = ws + off;
  size_t szB_nms = (size_t)NSLICE*4 + (size_t)NSLICE*MAXB*4*2;              // 257,280
  size_t szB_cut = (size_t)NSLICE*4*2;                                      // 2,560
  off += (szB_nms > szB_cut ? szB_nms : szB_cut);
  if (ws_size < off) return;  // 68,874,496 bytes

  unsigned short* histc = (unsigned short*)A;
  float* tk_prob = (float*)A;
  int*   tk_n    = (int*)(A + (size_t)NSLICE*KPRE*4);
  unsigned* cutKey = (unsigned*)Bp;
  int*      cutM   = (int*)(Bp + (size_t)NSLICE*4);
  int*   nms_cnt   = (int*)Bp;
  float* nms_score = (float*)(Bp + (size_t)NSLICE*4);
  int*   nms_k     = (int*)(Bp + (size_t)NSLICE*4 + (size_t)NSLICE*MAXB*4);

  hipLaunchKernelGGL(k_decode, dim3((BB*NN + 255)/256), dim3(256), 0, stream,
                     anchors, regression, boxes);
  hipLaunchKernelGGL(k_keys, dim3((NN + 63)/64, BB), dim3(256), 0, stream,
                     cls, keysT);
  hipLaunchKernelGGL(k_hist, dim3(NSLICE, CH), dim3(256), 0, stream,
                     (const uint4*)keysT, histc);
  hipLaunchKernelGGL(k_cutoff, dim3(NSLICE), dim3(256), 0, stream,
                     histc, cutKey, cutM);
  hipLaunchKernelGGL(k_selsort, dim3(NSLICE), dim3(1024), 0, stream,
                     keysT, cutKey, cutM, tk_prob, tk_n);
  hipLaunchKernelGGL(k_nms, dim3(NSLICE), dim3(64), 0, stream,
                     tk_prob, tk_n, (const float4*)boxes, nms_cnt, nms_score, nms_k);
  hipLaunchKernelGGL(k_merge, dim3(BB), dim3(256), 0, stream,
                     nms_cnt, nms_score, nms_k, tk_n, (const float4*)boxes, scale, out);
}